// Round 6
// baseline (156.812 us; speedup 1.0000x reference)
//
#include <hip/hip_runtime.h>

#define B 128
#define N 65536
#define D 512
#define K 5
#define M 256              // D * RATIO
#define GPB 128            // gallery rows per block (kernel1)
#define NBLK1 (N / GPB)    // 512 blocks
#define CHG 16             // g rows per chunk
#define NCHK (GPB / CHG)   // 8

typedef __attribute__((ext_vector_type(8))) short short8;
typedef __attribute__((ext_vector_type(4))) float f32x4;

// pack two fp32 -> one u32 of 2 bf16 (truncation) via v_perm_b32.
__device__ __forceinline__ unsigned int pack_bf2(float lo, float hi) {
    return __builtin_amdgcn_perm(__float_as_uint(hi), __float_as_uint(lo), 0x07060302u);
}

__device__ __forceinline__ void top5_insert(float v, int gi, float tv[K], int ti[K]) {
    // descending by value, ties broken by lower index (matches lax.top_k)
    if (v > tv[K - 1] || (v == tv[K - 1] && gi < ti[K - 1])) {
        tv[K - 1] = v; ti[K - 1] = gi;
        #pragma unroll
        for (int k = K - 1; k > 0; --k) {
            bool sw = (tv[k] > tv[k - 1]) || (tv[k] == tv[k - 1] && ti[k] < ti[k - 1]);
            if (sw) {
                float fv = tv[k]; tv[k] = tv[k - 1]; tv[k - 1] = fv;
                int fi = ti[k]; ti[k] = ti[k - 1]; ti[k - 1] = fi;
            }
        }
    }
}

// Kernel 0: convert t_f (128x512 fp32) -> bf16 once. L2-resident thereafter.
__global__ __launch_bounds__(256) void k0_cvt_t(const float* __restrict__ t_f,
                                                unsigned int* __restrict__ t_bf) {
    int i = blockIdx.x * 256 + threadIdx.x;   // float4 index, 16384 total
    float4 v = reinterpret_cast<const float4*>(t_f)[i];
    uint2 p;
    p.x = pack_bf2(v.x, v.y);
    p.y = pack_bf2(v.z, v.w);
    reinterpret_cast<uint2*>(t_bf)[i] = p;
}

// Kernel 1: bf16 MFMA sims. Block = 8 waves, all 128 b x 128 g rows. Wave w
// owns b-rows [16w,16w+16): A-fragments PINNED in 64 VGPRs via empty inline
// asm (R4/R5 lesson: the allocator rematerialized these loads every chunk,
// turning the K-loop into an L2-latency loop). Gallery staged per 16-g chunk
// into LDS (lane-contiguous writes, contiguous wave reads), double-buffered,
// one barrier per chunk, next chunk's loads issued before compute. Two
// independent MFMA chains. Per-lane packed top-5, shfl_xor merge.
__global__ __launch_bounds__(512, 2) void k1_sims_topk(const unsigned short* __restrict__ t_bf,
                                                       const float* __restrict__ gal,
                                                       float2* __restrict__ partial,
                                                       unsigned long long* __restrict__ mask64,
                                                       unsigned int* __restrict__ counter) {
    __shared__ unsigned short gLds[2][CHG * D];   // 2 x 16384 B
    __shared__ float normP[2][CHG][8];            // 1024 B

    const int tid = threadIdx.x;
    const int blk = blockIdx.x;
    const int lane = tid & 63;
    const int w = tid >> 6;
    const int l15 = lane & 15;
    const int l4 = lane >> 4;

    if (blk == 0) {
        if (tid < (D / 64)) mask64[tid] = ~0ull;   // init AND bitmap
        if (tid == 8) *counter = 0u;               // completion counter for k23
    }

    // staging geometry: thread covers g-row (lane>>2), k-cols {w*32, 256+w*32} + (lane&3)*8
    const int srow = lane >> 2;
    const int scol = w * 32 + (lane & 3) * 8;
    const float* gsrc0 = gal + ((size_t)blk * GPB + srow) * D + scol;

    // issue chunk-0 gallery loads first
    float4 st[4];
    #pragma unroll
    for (int i = 0; i < 2; ++i) {
        st[i]     = *reinterpret_cast<const float4*>(gsrc0 + i * 4);
        st[i + 2] = *reinterpret_cast<const float4*>(gsrc0 + 256 + i * 4);
    }

    // A fragments: wave's 16 b-rows (row = l15), bf16, PINNED. 64 VGPRs.
    short8 afr[16];
    {
        const unsigned short* tp = t_bf + (size_t)(w * 16 + l15) * D + l4 * 8;
        #pragma unroll
        for (int ks = 0; ks < 16; ++ks) {
            uint4 q = *reinterpret_cast<const uint4*>(tp + ks * 32);
            asm volatile("" : "+v"(q.x), "+v"(q.y), "+v"(q.z), "+v"(q.w));
            afr[ks] = *reinterpret_cast<short8*>(&q);
        }
    }

    // packed top-5 lists: lst[r] for b-row w*16 + l4*4 + r, over g ≡ l15 (mod 16)
    float lst[4][K];
    #pragma unroll
    for (int r = 0; r < 4; ++r)
        #pragma unroll
        for (int k = 0; k < K; ++k) lst[r][k] = -1e30f;

    // stage chunk 0 into buf 0
    {
        float nr = 0.f;
        #pragma unroll
        for (int i = 0; i < 4; ++i) {
            nr = fmaf(st[i].x, st[i].x, nr);
            nr = fmaf(st[i].y, st[i].y, nr);
            nr = fmaf(st[i].z, st[i].z, nr);
            nr = fmaf(st[i].w, st[i].w, nr);
        }
        char* LB = reinterpret_cast<char*>(&gLds[0][0]);
        uint4 q0, q1;
        q0.x = pack_bf2(st[0].x, st[0].y); q0.y = pack_bf2(st[0].z, st[0].w);
        q0.z = pack_bf2(st[1].x, st[1].y); q0.w = pack_bf2(st[1].z, st[1].w);
        q1.x = pack_bf2(st[2].x, st[2].y); q1.y = pack_bf2(st[2].z, st[2].w);
        q1.z = pack_bf2(st[3].x, st[3].y); q1.w = pack_bf2(st[3].z, st[3].w);
        *reinterpret_cast<uint4*>(LB + tid * 16) = q0;
        *reinterpret_cast<uint4*>(LB + 8192 + tid * 16) = q1;
        nr += __shfl_xor(nr, 1);
        nr += __shfl_xor(nr, 2);
        if ((lane & 3) == 0) normP[0][srow][w] = nr;
    }
    __syncthreads();

    for (int c = 0; c < NCHK; ++c) {
        const int buf = c & 1;
        // issue next chunk's global loads (hide latency under MFMA)
        if (c + 1 < NCHK) {
            const float* gs = gsrc0 + (size_t)(c + 1) * CHG * D;
            #pragma unroll
            for (int i = 0; i < 2; ++i) {
                st[i]     = *reinterpret_cast<const float4*>(gs + i * 4);
                st[i + 2] = *reinterpret_cast<const float4*>(gs + 256 + i * 4);
            }
        }
        // compute chunk c: two independent MFMA chains (8 deep each)
        f32x4 acc0 = (f32x4)0.0f, acc1 = (f32x4)0.0f;
        const unsigned short* Lr = &gLds[buf][0];
        const int foff = l15 * 32 + l4 * 8;    // ushort offset within k-slice
        #pragma unroll
        for (int ks = 0; ks < 16; ks += 2) {
            short8 b0 = *reinterpret_cast<const short8*>(Lr + ks * 512 + foff);
            short8 b1 = *reinterpret_cast<const short8*>(Lr + (ks + 1) * 512 + foff);
            acc0 = __builtin_amdgcn_mfma_f32_16x16x32_bf16(afr[ks], b0, acc0, 0, 0, 0);
            acc1 = __builtin_amdgcn_mfma_f32_16x16x32_bf16(afr[ks + 1], b1, acc1, 0, 0, 0);
        }
        // per-g scale = rsqrt(sum of 8 wave-partials)
        f32x4 n0 = *reinterpret_cast<const f32x4*>(&normP[buf][l15][0]);
        f32x4 n1 = *reinterpret_cast<const f32x4*>(&normP[buf][l15][4]);
        float sml = (n0[0] + n0[1]) + (n0[2] + n0[3]) + (n1[0] + n1[1]) + (n1[2] + n1[3]);
        float sc = rsqrtf(sml);
        unsigned meta = (unsigned)(c * CHG + l15);   // local g-index, 0..127
        #pragma unroll
        for (int r = 0; r < 4; ++r) {
            float s = (acc0[r] + acc1[r]) * sc;
            float sp = __uint_as_float((__float_as_uint(s) & 0xFFFFFF00u) | meta);
            if (sp > lst[r][K - 1]) {
                lst[r][K - 1] = sp;
                #pragma unroll
                for (int k = K - 1; k > 0; --k)
                    if (lst[r][k] > lst[r][k - 1]) {
                        float t2 = lst[r][k]; lst[r][k] = lst[r][k - 1]; lst[r][k - 1] = t2;
                    }
            }
        }
        // stage chunk c+1 into the other buffer
        if (c + 1 < NCHK) {
            float nr = 0.f;
            #pragma unroll
            for (int i = 0; i < 4; ++i) {
                nr = fmaf(st[i].x, st[i].x, nr);
                nr = fmaf(st[i].y, st[i].y, nr);
                nr = fmaf(st[i].z, st[i].z, nr);
                nr = fmaf(st[i].w, st[i].w, nr);
            }
            char* LB = reinterpret_cast<char*>(&gLds[buf ^ 1][0]);
            uint4 q0, q1;
            q0.x = pack_bf2(st[0].x, st[0].y); q0.y = pack_bf2(st[0].z, st[0].w);
            q0.z = pack_bf2(st[1].x, st[1].y); q0.w = pack_bf2(st[1].z, st[1].w);
            q1.x = pack_bf2(st[2].x, st[2].y); q1.y = pack_bf2(st[2].z, st[2].w);
            q1.z = pack_bf2(st[3].x, st[3].y); q1.w = pack_bf2(st[3].z, st[3].w);
            *reinterpret_cast<uint4*>(LB + tid * 16) = q0;
            *reinterpret_cast<uint4*>(LB + 8192 + tid * 16) = q1;
            nr += __shfl_xor(nr, 1);
            nr += __shfl_xor(nr, 2);
            if ((lane & 3) == 0) normP[buf ^ 1][srow][w] = nr;
        }
        __syncthreads();
    }

    // merge the 16 g-residues within each l4 group (lists stay packed)
    #pragma unroll
    for (int mk = 1; mk <= 8; mk <<= 1) {
        #pragma unroll
        for (int r = 0; r < 4; ++r) {
            float inc[K];
            #pragma unroll
            for (int k = 0; k < K; ++k) inc[k] = __shfl_xor(lst[r][k], mk);
            #pragma unroll
            for (int k = 0; k < K; ++k) {
                if (inc[k] > lst[r][K - 1]) {
                    lst[r][K - 1] = inc[k];
                    #pragma unroll
                    for (int q = K - 1; q > 0; --q)
                        if (lst[r][q] > lst[r][q - 1]) {
                            float t2 = lst[r][q]; lst[r][q] = lst[r][q - 1]; lst[r][q - 1] = t2;
                        }
                }
            }
        }
    }

    // writers: lane l15==r writes list r (all 16 lanes of a group converged)
    #pragma unroll
    for (int rr = 0; rr < 4; ++rr) {
        if (l15 == rr) {
            int b = w * 16 + l4 * 4 + rr;
            #pragma unroll
            for (int k = 0; k < K; ++k) {
                unsigned sp = __float_as_uint(lst[rr][k]);
                int g = blk * GPB + (int)(sp & 0xFFu);
                partial[((size_t)b * NBLK1 + blk) * K + k] = make_float2(lst[rr][k], __int_as_float(g));
            }
        }
    }
}

// Kernel 23 (fused merge + membership + final mask): block b merges its 512
// partial top-5 lists -> top-5 global rows, computes bottom-m membership of
// |gal[row,c]*s_f[b,c]| per row (per-row norms are positive constants ->
// ordering matches the reference's normalized products), ANDs into the global
// bitmap; the LAST block to finish emits the output mask.
__global__ __launch_bounds__(512) void k23_merge_member(const float2* __restrict__ partial,
                                                        const float* __restrict__ s_f,
                                                        const float* __restrict__ gal,
                                                        unsigned long long* __restrict__ mask64,
                                                        unsigned int* __restrict__ counter,
                                                        float* __restrict__ out) {
    __shared__ float2 cand[NBLK1 * K];          // 20480 B
    __shared__ int idxS[K];
    __shared__ float pS[D];
    __shared__ unsigned long long andW[D / 64];
    __shared__ unsigned long long maskLds[D / 64];
    __shared__ int isLast;

    const int b = blockIdx.x;
    const int p = threadIdx.x;
    if (p < (D / 64)) andW[p] = ~0ull;

    float mv[K]; int mi[K];
    #pragma unroll
    for (int k = 0; k < K; ++k) {
        float2 c = partial[((size_t)b * NBLK1 + p) * K + k];
        mv[k] = c.x; mi[k] = __float_as_int(c.y);
        cand[p * K + k] = c;
    }
    __syncthreads();
    for (int s = NBLK1 / 2; s >= 1; s >>= 1) {
        if (p < s) {
            #pragma unroll
            for (int k = 0; k < K; ++k) {
                float2 c = cand[(p + s) * K + k];
                top5_insert(c.x, __float_as_int(c.y), mv, mi);
            }
            #pragma unroll
            for (int k = 0; k < K; ++k)
                cand[p * K + k] = make_float2(mv[k], __int_as_float(mi[k]));
        }
        __syncthreads();
    }
    if (p == 0) {
        #pragma unroll
        for (int k = 0; k < K; ++k) idxS[k] = mi[k];
    }
    __syncthreads();

    const float sv = s_f[(size_t)b * D + p];
    for (int k = 0; k < K; ++k) {
        const int row = idxS[k];
        float pv = fabsf(gal[(size_t)row * D + p] * sv);
        __syncthreads();          // guard pS reuse from previous iteration
        pS[p] = pv;
        __syncthreads();
        int cnt = 0;
        #pragma unroll 8
        for (int c2 = 0; c2 < D; ++c2) {
            float o = pS[c2];
            cnt += (o < pv || (o == pv && c2 < p)) ? 1 : 0;
        }
        unsigned long long bm = __ballot(cnt < M);
        if ((p & 63) == 0) andW[p >> 6] &= bm;
    }
    __syncthreads();
    if (p < (D / 64)) atomicAnd(&mask64[p], andW[p]);
    __syncthreads();
    if (p == 0) {
        __threadfence();
        unsigned done = atomicAdd(counter, 1u);
        isLast = (done == B - 1) ? 1 : 0;
    }
    __syncthreads();
    if (isLast) {
        if (p < (D / 64)) {
            __threadfence();
            maskLds[p] = atomicAnd(&mask64[p], ~0ull);   // coherent read
        }
        __syncthreads();
        out[p] = ((maskLds[p >> 6] >> (p & 63)) & 1ull) ? 0.0f : 1.0f;
    }
}

extern "C" void kernel_launch(void* const* d_in, const int* in_sizes, int n_in,
                              void* d_out, int out_size, void* d_ws, size_t ws_size,
                              hipStream_t stream) {
    (void)in_sizes; (void)n_in; (void)out_size; (void)ws_size;
    const float* s_f = (const float*)d_in[0];
    const float* t_f = (const float*)d_in[1];
    const float* gal = (const float*)d_in[2];
    float* out = (float*)d_out;

    char* ws = (char*)d_ws;
    size_t off_tbf = 0;
    size_t sz_tbf = (size_t)B * D * 2;                            // 131072 B
    size_t off_partial = off_tbf + sz_tbf;
    size_t sz_partial = (size_t)NBLK1 * B * K * sizeof(float2);   // 2,621,440 B
    size_t off_mask = off_partial + sz_partial;
    size_t off_cnt = off_mask + (D / 64) * sizeof(unsigned long long);

    unsigned int* t_bf = (unsigned int*)(ws + off_tbf);
    float2* partial = (float2*)(ws + off_partial);
    unsigned long long* mask64 = (unsigned long long*)(ws + off_mask);
    unsigned int* counter = (unsigned int*)(ws + off_cnt);

    hipLaunchKernelGGL(k0_cvt_t, dim3(B * D / 4 / 256), dim3(256), 0, stream, t_f, t_bf);
    hipLaunchKernelGGL(k1_sims_topk, dim3(NBLK1), dim3(512), 0, stream,
                       (const unsigned short*)t_bf, gal, partial, mask64, counter);
    hipLaunchKernelGGL(k23_merge_member, dim3(B), dim3(512), 0, stream,
                       partial, s_f, gal, mask64, counter, out);
}